// Round 6
// baseline (503.768 us; speedup 1.0000x reference)
//
#include <hip/hip_runtime.h>

#define BATCH 64
#define HH 512
#define WW 512
#define TH 32                  // output rows per strip
#define KS 11
#define PADK 5
#define NIN (TH + 2 * PADK)    // 42 input rows per strip
#define WS4 70                 // float4 slots per wave-row: 3 halo + 64 own + 3 halo
#define NPIX (64.0 * 512.0 * 512.0)

// 256 threads = 4 waves; wave w owns cols [128w, 128w+128), lane l owns output
// cols 128w+2l, +1. Staging is WAVE-PRIVATE: each wave stages its 128 cols +
// 6-px halo per side into its own LDS region (halo pairs re-loaded from global
// by lanes 0..5; zero-filled at image edges). Within a wave, DS ops are
// in-order and lgkmcnt covers the RAW -> NO __syncthreads in the main loop.
// This removes round-5's per-chunk barrier drain (s_waitcnt vmcnt(0) before
// s_barrier parked all 4 waves in lockstep against ~900-cy HBM latency).
// Ring-11 = 88 NAMED scalars (round-3-proven spill-free); 4-row chunks
// double-buffered per wave (parity k&1); lcm(4,11)=44 -> 11 chunks fully
// unrolled with literal parity and literal ring rotations.
__global__ void __launch_bounds__(256, 2) ssim_main_kernel(
    const float* __restrict__ img1, const float* __restrict__ img2,
    double* __restrict__ accum) {
  constexpr float GA[KS] = {
      0.00102838f, 0.00759884f, 0.03600087f, 0.10936069f, 0.21300553f,
      0.26601172f, 0.21300553f, 0.10936069f, 0.03600087f, 0.00759884f,
      0.00102838f};
  const float C1v = 1e-4f, C2v = 9e-4f;

  const int t  = threadIdx.x;          // 0..255
  const int l  = t & 63;               // lane
  const int w  = t >> 6;               // wave
  const int r0 = blockIdx.x * TH;      // first output row of strip
  const int b  = blockIdx.y;           // batch index

  const float2* __restrict__ pp1 =
      reinterpret_cast<const float2*>(img1 + (size_t)b * HH * WW);
  const float2* __restrict__ pp2 =
      reinterpret_cast<const float2*>(img2 + (size_t)b * HH * WW);

  // Wave-private: sh[wave][buf][row][slot]. Slot s = px pair (2s-6, 2s-5)
  // relative to wave base col 128w. Own pair of lane l -> slot l+3.
  __shared__ float4 sh[4][2][4][WS4];
  __shared__ float wsum[4];

  // Halo constants (per-thread invariant): lanes 0..2 -> left slots 0..2,
  // lanes 3..5 -> right slots 67..69. Global float2 index of halo pair.
  const int  hs   = (l < 3) ? l : (l + 64);
  const int  hidx = 64 * w + hs - 3;
  const bool hval = (l < 6) && ((unsigned)hidx < (unsigned)(WW / 2));

  // Ring: 88 named scalars; slot s holds h-conv of input row rc, rc%11==s.
#define DECLR(s) float xA##s = 0.f, xB##s = 0.f, xQ##s = 0.f, xP##s = 0.f, \
                       yA##s = 0.f, yB##s = 0.f, yQ##s = 0.f, yP##s = 0.f;
  DECLR(0) DECLR(1) DECLR(2) DECLR(3) DECLR(4) DECLR(5)
  DECLR(6) DECLR(7) DECLR(8) DECLR(9) DECLR(10)

  float2 ta0, ta1, ta2, ta3, tb0, tb1, tb2, tb3;  // own-pair staging regs
  float2 ha0, ha1, ha2, ha3, hb0, hb1, hb2, hb3;  // halo-pair staging regs
  float local = 0.f;

  // Load chunk k_ rows into regs (rows >= NIN constexpr-skipped; row validity
  // is block-uniform; halo validity lane-divergent).
#define LD1(k_, j_)                                                     \
  {                                                                     \
    constexpr int rc_ = 4 * (k_) + (j_);                                \
    ta##j_ = make_float2(0.f, 0.f); tb##j_ = make_float2(0.f, 0.f);     \
    ha##j_ = make_float2(0.f, 0.f); hb##j_ = make_float2(0.f, 0.f);     \
    if constexpr (rc_ < NIN) {                                          \
      const int rr_ = r0 - PADK + rc_;                                  \
      if ((unsigned)rr_ < HH) {                                         \
        const int off_ = rr_ * (WW / 2);                                \
        ta##j_ = pp1[off_ + t];                                         \
        tb##j_ = pp2[off_ + t];                                         \
        if (hval) {                                                     \
          ha##j_ = pp1[off_ + hidx];                                    \
          hb##j_ = pp2[off_ + hidx];                                    \
        }                                                               \
      }                                                                 \
    }                                                                   \
  }
#define LOADC(k_) { LD1(k_, 0) LD1(k_, 1) LD1(k_, 2) LD1(k_, 3) }

  // Write staged regs of chunk k_ into this wave's buffer k_&1. Lanes 0..5
  // additionally write the halo slots (zeros when out of image).
#define WR1(k_, j_)                                                     \
  {                                                                     \
    constexpr int rc_ = 4 * (k_) + (j_);                                \
    if constexpr (rc_ < NIN) {                                          \
      sh[w][(k_) & 1][j_][l + 3] =                                      \
          make_float4(ta##j_.x, tb##j_.x, ta##j_.y, tb##j_.y);          \
      if (l < 6)                                                        \
        sh[w][(k_) & 1][j_][hs] =                                       \
            make_float4(ha##j_.x, hb##j_.x, ha##j_.y, hb##j_.y);        \
    }                                                                   \
  }
#define WRITEC(k_) { WR1(k_, 0) WR1(k_, 1) WR1(k_, 2) WR1(k_, 3) }

  // Horizontal conv of wave-row j_ of buffer B_ -> ring slot S. 7 b128
  // reads; slot l+kk = px pair (j0=2kk-1, j1=2kk) rel. to window start
  // 2l-5; col0 (2l) taps GA[j], col1 (2l+1) GA[j-1]. (Verified round 3/5.)
#define HBODY(B_, j_, S)                                                      \
  {                                                                           \
    float h0a = 0.f, h0b = 0.f, h0q = 0.f, h0p = 0.f;                         \
    float h1a = 0.f, h1b = 0.f, h1q = 0.f, h1p = 0.f;                         \
    _Pragma("unroll")                                                         \
    for (int kk = 0; kk < 7; ++kk) {                                          \
      const float4 v = sh[w][B_][j_][l + kk];                                 \
      if (kk >= 1) { /* px j0 = 2kk-1 : a=v.x b=v.y */                        \
        const float qv_ = fmaf(v.x, v.x, v.y * v.y);                          \
        const float pv_ = v.x * v.y;                                          \
        if (kk <= 5) {                                                        \
          const float w_ = GA[2 * kk - 1];                                    \
          h0a = fmaf(w_, v.x, h0a); h0b = fmaf(w_, v.y, h0b);                 \
          h0q = fmaf(w_, qv_, h0q); h0p = fmaf(w_, pv_, h0p);                 \
        }                                                                     \
        {                                                                     \
          const float w_ = GA[2 * kk - 2];                                    \
          h1a = fmaf(w_, v.x, h1a); h1b = fmaf(w_, v.y, h1b);                 \
          h1q = fmaf(w_, qv_, h1q); h1p = fmaf(w_, pv_, h1p);                 \
        }                                                                     \
      }                                                                       \
      if (kk <= 5) { /* px j1 = 2kk : a=v.z b=v.w */                          \
        const float qv_ = fmaf(v.z, v.z, v.w * v.w);                          \
        const float pv_ = v.z * v.w;                                          \
        {                                                                     \
          const float w_ = GA[2 * kk];                                        \
          h0a = fmaf(w_, v.z, h0a); h0b = fmaf(w_, v.w, h0b);                 \
          h0q = fmaf(w_, qv_, h0q); h0p = fmaf(w_, pv_, h0p);                 \
        }                                                                     \
        if (kk >= 1) {                                                        \
          const float w_ = GA[2 * kk - 1];                                    \
          h1a = fmaf(w_, v.z, h1a); h1b = fmaf(w_, v.w, h1b);                 \
          h1q = fmaf(w_, qv_, h1q); h1p = fmaf(w_, pv_, h1p);                 \
        }                                                                     \
      }                                                                       \
    }                                                                         \
    xA##S = h0a; xB##S = h0b; xQ##S = h0q; xP##S = h0p;                       \
    yA##S = h1a; yB##S = h1b; yQ##S = h1q; yP##S = h1p;                       \
  }

  // Vertical conv: explicit rotation, slot names literal.
#define VC(P, s0,s1,s2v,s3,s4v,s5,s6v,s7,s8,s9,s10)                           \
  fmaf(GA[10], P##s10, fmaf(GA[9], P##s9, fmaf(GA[8], P##s8,                  \
  fmaf(GA[7], P##s7, fmaf(GA[6], P##s6v, fmaf(GA[5], P##s5,                   \
  fmaf(GA[4], P##s4v, fmaf(GA[3], P##s3, fmaf(GA[2], P##s2v,                  \
  fmaf(GA[1], P##s1, GA[0] * P##s0))))))))))

#define SSIMACC                                                               \
  {                                                                           \
    const float m1s = m1 * m1, m2s = m2 * m2, m12 = m1 * m2;                  \
    const float s12 = mp - m12;                                               \
    const float sqq = mq - m1s - m2s;                                         \
    const float num = fmaf(2.f, m12, C1v) * fmaf(2.f, s12, C2v);              \
    const float den = (m1s + m2s + C1v) * (sqq + C2v);                        \
    local = fmaf(num, __builtin_amdgcn_rcpf(den), local);                     \
  }

#define VOUTBODY(s0,s1,s2v,s3,s4v,s5,s6v,s7,s8,s9,s10)                        \
  {                                                                           \
    {                                                                         \
      const float m1 = VC(xA, s0,s1,s2v,s3,s4v,s5,s6v,s7,s8,s9,s10);          \
      const float m2 = VC(xB, s0,s1,s2v,s3,s4v,s5,s6v,s7,s8,s9,s10);          \
      const float mq = VC(xQ, s0,s1,s2v,s3,s4v,s5,s6v,s7,s8,s9,s10);          \
      const float mp = VC(xP, s0,s1,s2v,s3,s4v,s5,s6v,s7,s8,s9,s10);          \
      SSIMACC                                                                 \
    }                                                                         \
    {                                                                         \
      const float m1 = VC(yA, s0,s1,s2v,s3,s4v,s5,s6v,s7,s8,s9,s10);          \
      const float m2 = VC(yB, s0,s1,s2v,s3,s4v,s5,s6v,s7,s8,s9,s10);          \
      const float mq = VC(yQ, s0,s1,s2v,s3,s4v,s5,s6v,s7,s8,s9,s10);          \
      const float mp = VC(yP, s0,s1,s2v,s3,s4v,s5,s6v,s7,s8,s9,s10);          \
      SSIMACC                                                                 \
    }                                                                         \
  }

#define ROT0  0,1,2,3,4,5,6,7,8,9,10
#define ROT1  1,2,3,4,5,6,7,8,9,10,0
#define ROT2  2,3,4,5,6,7,8,9,10,0,1
#define ROT3  3,4,5,6,7,8,9,10,0,1,2
#define ROT4  4,5,6,7,8,9,10,0,1,2,3
#define ROT5  5,6,7,8,9,10,0,1,2,3,4
#define ROT6  6,7,8,9,10,0,1,2,3,4,5
#define ROT7  7,8,9,10,0,1,2,3,4,5,6
#define ROT8  8,9,10,0,1,2,3,4,5,6,7
#define ROT9  9,10,0,1,2,3,4,5,6,7,8
#define ROT10 10,0,1,2,3,4,5,6,7,8,9
#define VOUTE(...) VOUTBODY(__VA_ARGS__)

#define ROWH(B_, j_, S)        { HBODY(B_, j_, S) }
#define ROWO(B_, j_, S, R_)    { HBODY(B_, j_, S) VOUTE(R_) }

  // Prologue: stage chunk 0 (buf0), prefetch chunk 1 regs. No barrier:
  // the wave's own DS order + lgkmcnt is the only dependence.
  LOADC(0) WRITEC(0) LOADC(1)

  // Per chunk k: write prefetched chunk k+1 into buf (k+1)&1 (this wave's
  // own reads of that buf finished in chunk k-1, and DS is in-order within
  // a wave), issue loads for k+2, compute chunk k. rc = 4k+j, S = rc%11,
  // outputs when rc >= 10.
  // k=0: rc 0-3
  WRITEC(1) LOADC(2)
  ROWH(0,0,0) ROWH(0,1,1) ROWH(0,2,2) ROWH(0,3,3)
  // k=1: rc 4-7
  WRITEC(2) LOADC(3)
  ROWH(1,0,4) ROWH(1,1,5) ROWH(1,2,6) ROWH(1,3,7)
  // k=2: rc 8-11 (rc10,11 emit output rows 0,1)
  WRITEC(3) LOADC(4)
  ROWH(0,0,8) ROWH(0,1,9)
  ROWO(0,2,10, ROT0) ROWO(0,3,0, ROT1)
  // k=3: rc 12-15
  WRITEC(4) LOADC(5)
  ROWO(1,0,1, ROT2) ROWO(1,1,2, ROT3) ROWO(1,2,3, ROT4) ROWO(1,3,4, ROT5)
  // k=4: rc 16-19
  WRITEC(5) LOADC(6)
  ROWO(0,0,5, ROT6) ROWO(0,1,6, ROT7) ROWO(0,2,7, ROT8) ROWO(0,3,8, ROT9)
  // k=5: rc 20-23
  WRITEC(6) LOADC(7)
  ROWO(1,0,9, ROT10) ROWO(1,1,10, ROT0) ROWO(1,2,0, ROT1) ROWO(1,3,1, ROT2)
  // k=6: rc 24-27
  WRITEC(7) LOADC(8)
  ROWO(0,0,2, ROT3) ROWO(0,1,3, ROT4) ROWO(0,2,4, ROT5) ROWO(0,3,5, ROT6)
  // k=7: rc 28-31
  WRITEC(8) LOADC(9)
  ROWO(1,0,6, ROT7) ROWO(1,1,7, ROT8) ROWO(1,2,8, ROT9) ROWO(1,3,9, ROT10)
  // k=8: rc 32-35
  WRITEC(9) LOADC(10)
  ROWO(0,0,10, ROT0) ROWO(0,1,0, ROT1) ROWO(0,2,1, ROT2) ROWO(0,3,2, ROT3)
  // k=9: rc 36-39 (chunk 10 holds only rc 40,41; rc 42,43 constexpr-cut)
  WRITEC(10)
  ROWO(1,0,3, ROT4) ROWO(1,1,4, ROT5) ROWO(1,2,5, ROT6) ROWO(1,3,6, ROT7)
  // k=10: rc 40,41 (output rows 30,31)
  ROWO(0,0,7, ROT8) ROWO(0,1,8, ROT9)

  // Block reduction: wave64 shuffle -> LDS -> one double atomic per block.
#pragma unroll
  for (int off = 32; off > 0; off >>= 1) local += __shfl_down(local, off, 64);
  if (l == 0) wsum[w] = local;
  __syncthreads();
  if (t == 0) {
    float s = wsum[0] + wsum[1] + wsum[2] + wsum[3];
    atomicAdd(accum, (double)s);
  }
}

__global__ void ssim_final_kernel(const double* __restrict__ accum,
                                  float* __restrict__ out) {
  out[0] = 1.0f - (float)(accum[0] / NPIX);
}

extern "C" void kernel_launch(void* const* d_in, const int* in_sizes, int n_in,
                              void* d_out, int out_size, void* d_ws, size_t ws_size,
                              hipStream_t stream) {
  const float* img1 = (const float*)d_in[0];
  const float* img2 = (const float*)d_in[1];
  double* accum = (double*)d_ws;
  hipMemsetAsync(accum, 0, sizeof(double), stream);

  dim3 grid(HH / TH, BATCH);
  ssim_main_kernel<<<grid, 256, 0, stream>>>(img1, img2, accum);
  ssim_final_kernel<<<1, 1, 0, stream>>>(accum, (float*)d_out);
}

// Round 7
// 180.075 us; speedup vs baseline: 2.7976x; 2.7976x over previous
//
#include <hip/hip_runtime.h>

#define BATCH 64
#define HH 512
#define WW 512
#define TH 32                  // output rows per strip
#define KS 11
#define PADK 5
#define NIN (TH + 2 * PADK)    // 42 valid input rows per strip (44 slots, 2 cut)
#define LROW (WW + 2 * PADK)   // 522 float4 slots per staged row
#define NPIX (64.0 * 512.0 * 512.0)

// Baseline-structure kernel (best measured: 88.6 us) with its one proven
// defect fixed. 512 threads; thread c owns output column c of a TH=32-row
// strip. LDS stages float4{a, b, a^2+b^2, ab} per pixel (computed ONCE at
// staging — no redundant recompute on the 11-reader path), 4-row chunks,
// double-buffered, ONE barrier per chunk (dbuf parity: chunk k writes buf
// k&1 while any straggler still reads buf (k-1)&1), loads prefetched one
// full chunk ahead into NAMED regs. The vertical 11-tap ring is 44 NAMED
// scalars: the baseline's rA[i%11] arrays were scratch-allocated (SROA
// runs before unrolling -> 53 MB WRITE_SIZE, ~25 floats spilled); named
// scalars are the round-3/5-proven fix (WRITE_SIZE 32 B). Barriers are
// kept: round 6 proved they double as live-range fences (removing them
// blew the allocator: 651 MB scratch).
__global__ void __launch_bounds__(512, 2) ssim_main_kernel(
    const float* __restrict__ img1, const float* __restrict__ img2,
    double* __restrict__ accum) {
  constexpr float GA[KS] = {
      0.00102838f, 0.00759884f, 0.03600087f, 0.10936069f, 0.21300553f,
      0.26601172f, 0.21300553f, 0.10936069f, 0.03600087f, 0.00759884f,
      0.00102838f};
  const float C1v = 1e-4f, C2v = 9e-4f;

  const int c  = threadIdx.x;          // column 0..511
  const int r0 = blockIdx.x * TH;      // first output row of strip
  const int b  = blockIdx.y;           // batch index

  const float* __restrict__ p1 = img1 + (size_t)b * (HH * WW);
  const float* __restrict__ p2 = img2 + (size_t)b * (HH * WW);

  __shared__ float4 s4[2][4][LROW];    // pixel x -> slot x+PADK
  __shared__ float wsum[8];

  // Zero horizontal pads of both buffers once (slots 0..4 and 517..521).
  if (c < PADK) {
#pragma unroll
    for (int bi = 0; bi < 2; ++bi)
#pragma unroll
      for (int r = 0; r < 4; ++r) {
        s4[bi][r][c]             = make_float4(0.f, 0.f, 0.f, 0.f);
        s4[bi][r][WW + PADK + c] = make_float4(0.f, 0.f, 0.f, 0.f);
      }
  }

  // Ring: 44 named scalars; slot s holds h-conv of input row rc, rc%11==s.
#define DECLR(s) float zA##s = 0.f, zB##s = 0.f, zQ##s = 0.f, zP##s = 0.f;
  DECLR(0) DECLR(1) DECLR(2) DECLR(3) DECLR(4) DECLR(5)
  DECLR(6) DECLR(7) DECLR(8) DECLR(9) DECLR(10)

  float pa0, pa1, pa2, pa3, pb0, pb1, pb2, pb3;   // prefetch regs
  float local = 0.f;

  // Load chunk k_ rows into named regs (rows >= NIN constexpr-cut; row
  // validity is block-uniform).
#define LD1(k_, j_)                                                     \
  {                                                                     \
    constexpr int rc_ = 4 * (k_) + (j_);                                \
    pa##j_ = 0.f; pb##j_ = 0.f;                                         \
    if constexpr (rc_ < NIN) {                                          \
      const int rr_ = r0 - PADK + rc_;                                  \
      if ((unsigned)rr_ < HH) {                                         \
        const int off_ = rr_ * WW + c;                                  \
        pa##j_ = p1[off_];                                              \
        pb##j_ = p2[off_];                                              \
      }                                                                 \
    }                                                                   \
  }
#define LOADC(k_) { LD1(k_, 0) LD1(k_, 1) LD1(k_, 2) LD1(k_, 3) }

  // Stage chunk k_ into buffer k_&1: {a, b, a^2+b^2, ab}, one b128/row.
#define WR1(k_, j_)                                                     \
  {                                                                     \
    constexpr int rc_ = 4 * (k_) + (j_);                                \
    if constexpr (rc_ < NIN)                                            \
      s4[(k_) & 1][j_][PADK + c] = make_float4(                         \
          pa##j_, pb##j_, fmaf(pa##j_, pa##j_, pb##j_ * pb##j_),        \
          pa##j_ * pb##j_);                                             \
  }
#define WRITEC(k_) { WR1(k_, 0) WR1(k_, 1) WR1(k_, 2) WR1(k_, 3) }

  // Horizontal 11-tap conv of LDS row j_ of buffer bb_: 11 b128 reads,
  // 4 fma/tap (signals pre-packed). Result -> ring slot S (named).
#define HBODY(bb_, j_, S)                                               \
  {                                                                     \
    float h1 = 0.f, h2 = 0.f, hq = 0.f, hp = 0.f;                       \
    _Pragma("unroll")                                                   \
    for (int k = 0; k < KS; ++k) {                                      \
      const float4 v = s4[bb_][j_][c + k];                              \
      const float w_ = GA[k];                                           \
      h1 = fmaf(w_, v.x, h1);                                           \
      h2 = fmaf(w_, v.y, h2);                                           \
      hq = fmaf(w_, v.z, hq);                                           \
      hp = fmaf(w_, v.w, hp);                                           \
    }                                                                   \
    zA##S = h1; zB##S = h2; zQ##S = hq; zP##S = hp;                     \
  }

  // Vertical conv: explicit rotation, slot names literal.
#define VC(P, s0,s1,s2v,s3,s4v,s5,s6v,s7,s8,s9,s10)                     \
  fmaf(GA[10], P##s10, fmaf(GA[9], P##s9, fmaf(GA[8], P##s8,            \
  fmaf(GA[7], P##s7, fmaf(GA[6], P##s6v, fmaf(GA[5], P##s5,             \
  fmaf(GA[4], P##s4v, fmaf(GA[3], P##s3, fmaf(GA[2], P##s2v,            \
  fmaf(GA[1], P##s1, GA[0] * P##s0))))))))))

#define VOUTBODY(s0,s1,s2v,s3,s4v,s5,s6v,s7,s8,s9,s10)                  \
  {                                                                     \
    const float m1 = VC(zA, s0,s1,s2v,s3,s4v,s5,s6v,s7,s8,s9,s10);      \
    const float m2 = VC(zB, s0,s1,s2v,s3,s4v,s5,s6v,s7,s8,s9,s10);      \
    const float mq = VC(zQ, s0,s1,s2v,s3,s4v,s5,s6v,s7,s8,s9,s10);      \
    const float mp = VC(zP, s0,s1,s2v,s3,s4v,s5,s6v,s7,s8,s9,s10);      \
    const float m1s = m1 * m1, m2s = m2 * m2, m12 = m1 * m2;            \
    const float s12 = mp - m12;                                         \
    const float sqq = mq - m1s - m2s;                                   \
    const float num = fmaf(2.f, m12, C1v) * fmaf(2.f, s12, C2v);        \
    const float den = (m1s + m2s + C1v) * (sqq + C2v);                  \
    local = fmaf(num, __builtin_amdgcn_rcpf(den), local);               \
  }

#define ROT0  0,1,2,3,4,5,6,7,8,9,10
#define ROT1  1,2,3,4,5,6,7,8,9,10,0
#define ROT2  2,3,4,5,6,7,8,9,10,0,1
#define ROT3  3,4,5,6,7,8,9,10,0,1,2
#define ROT4  4,5,6,7,8,9,10,0,1,2,3
#define ROT5  5,6,7,8,9,10,0,1,2,3,4
#define ROT6  6,7,8,9,10,0,1,2,3,4,5
#define ROT7  7,8,9,10,0,1,2,3,4,5,6
#define ROT8  8,9,10,0,1,2,3,4,5,6,7
#define ROT9  9,10,0,1,2,3,4,5,6,7,8
#define ROT10 10,0,1,2,3,4,5,6,7,8,9
#define VOUTE(...) VOUTBODY(__VA_ARGS__)

#define ROWH(bb_, j_, S)      { HBODY(bb_, j_, S) }
#define ROWO(bb_, j_, S, R_)  { HBODY(bb_, j_, S) VOUTE(R_) }

  // Prologue: prefetch chunk 0.
  LOADC(0)

  // Per chunk ii (buf = ii&1): write staged regs; ONE barrier; prefetch
  // chunk ii+1 (latency hides under this chunk's 4x(11 reads + 44 fma));
  // compute the 4 rows. rc = 4*ii+j; ring slot S = rc%11; output row
  // rc-10 emitted when rc >= 10 using rotation start (rc+1)%11.
  // ii=0: rc 0-3
  WRITEC(0) __syncthreads(); LOADC(1)
  ROWH(0,0,0) ROWH(0,1,1) ROWH(0,2,2) ROWH(0,3,3)
  // ii=1: rc 4-7
  WRITEC(1) __syncthreads(); LOADC(2)
  ROWH(1,0,4) ROWH(1,1,5) ROWH(1,2,6) ROWH(1,3,7)
  // ii=2: rc 8-11 (rc10,11 -> output rows 0,1)
  WRITEC(2) __syncthreads(); LOADC(3)
  ROWH(0,0,8) ROWH(0,1,9)
  ROWO(0,2,10, ROT0) ROWO(0,3,0, ROT1)
  // ii=3: rc 12-15
  WRITEC(3) __syncthreads(); LOADC(4)
  ROWO(1,0,1, ROT2) ROWO(1,1,2, ROT3) ROWO(1,2,3, ROT4) ROWO(1,3,4, ROT5)
  // ii=4: rc 16-19
  WRITEC(4) __syncthreads(); LOADC(5)
  ROWO(0,0,5, ROT6) ROWO(0,1,6, ROT7) ROWO(0,2,7, ROT8) ROWO(0,3,8, ROT9)
  // ii=5: rc 20-23
  WRITEC(5) __syncthreads(); LOADC(6)
  ROWO(1,0,9, ROT10) ROWO(1,1,10, ROT0) ROWO(1,2,0, ROT1) ROWO(1,3,1, ROT2)
  // ii=6: rc 24-27
  WRITEC(6) __syncthreads(); LOADC(7)
  ROWO(0,0,2, ROT3) ROWO(0,1,3, ROT4) ROWO(0,2,4, ROT5) ROWO(0,3,5, ROT6)
  // ii=7: rc 28-31
  WRITEC(7) __syncthreads(); LOADC(8)
  ROWO(1,0,6, ROT7) ROWO(1,1,7, ROT8) ROWO(1,2,8, ROT9) ROWO(1,3,9, ROT10)
  // ii=8: rc 32-35
  WRITEC(8) __syncthreads(); LOADC(9)
  ROWO(0,0,10, ROT0) ROWO(0,1,0, ROT1) ROWO(0,2,1, ROT2) ROWO(0,3,2, ROT3)
  // ii=9: rc 36-39
  WRITEC(9) __syncthreads(); LOADC(10)
  ROWO(1,0,3, ROT4) ROWO(1,1,4, ROT5) ROWO(1,2,5, ROT6) ROWO(1,3,6, ROT7)
  // ii=10: rc 40,41 (output rows 30,31; rc 42,43 constexpr-cut)
  WRITEC(10) __syncthreads();
  ROWO(0,0,7, ROT8) ROWO(0,1,8, ROT9)

  // Block reduction: wave64 shuffle -> LDS -> one double atomic per block.
#pragma unroll
  for (int off = 32; off > 0; off >>= 1) local += __shfl_down(local, off, 64);
  const int wave = threadIdx.x >> 6;
  const int lane = threadIdx.x & 63;
  if (lane == 0) wsum[wave] = local;
  __syncthreads();
  if (threadIdx.x == 0) {
    float s = 0.f;
#pragma unroll
    for (int w = 0; w < 8; ++w) s += wsum[w];
    atomicAdd(accum, (double)s);
  }
}

__global__ void ssim_final_kernel(const double* __restrict__ accum,
                                  float* __restrict__ out) {
  out[0] = 1.0f - (float)(accum[0] / NPIX);
}

extern "C" void kernel_launch(void* const* d_in, const int* in_sizes, int n_in,
                              void* d_out, int out_size, void* d_ws, size_t ws_size,
                              hipStream_t stream) {
  const float* img1 = (const float*)d_in[0];
  const float* img2 = (const float*)d_in[1];
  double* accum = (double*)d_ws;
  hipMemsetAsync(accum, 0, sizeof(double), stream);

  dim3 grid(HH / TH, BATCH);
  ssim_main_kernel<<<grid, 512, 0, stream>>>(img1, img2, accum);
  ssim_final_kernel<<<1, 1, 0, stream>>>(accum, (float*)d_out);
}

// Round 8
// 178.992 us; speedup vs baseline: 2.8145x; 1.0060x over previous
//
#include <hip/hip_runtime.h>

#define BATCH 64
#define HH 512
#define WW 512
#define TH 32                  // output rows per strip
#define KS 11
#define PADK 5
#define NIN (TH + 2 * PADK)    // 42 valid input rows per strip (44 slots, 2 cut)
#define NP2 524                // float2 slots/row: 6 pad + 512 px + 6 pad
#define NPIX (64.0 * 512.0 * 512.0)

// Round-7 structure (proven 92%-of-LDS-roofline scheduling) with the LDS
// LAYOUT halved: stage float2{a,b} (8 B/px) instead of float4{a,b,q,p}.
// The 11-px window of column c spans exactly 6 float4 PAIRS for both
// parities (pr0 = (c+1)>>1) -> 6 ds_read_b128 + 1 ds_write_b64 per row
// vs 11 + 1 b128 before: LDS pipe work drops 144 -> 78 cyc/row/wave.
// q = a^2+b^2 and p = ab are recomputed at read time (+3 VALU/px); the
// parity-dependent tap alignment is 12 per-thread weight REGS selected
// once (w_j = odd ? G[j](j<11):0 : G[j-1](j>0):0) — no divergence.
// Kept from previous rounds (each proven): named-scalar ring-11 (spill
// fix, r3/r7), 4-row double-buffered chunks + ONE barrier per chunk
// (barriers double as live-range fences, r6), named prefetch regs,
// no launch_bounds tighter than (512,2) (cap-induced wholesale spill, r4).
__global__ void __launch_bounds__(512, 2) ssim_main_kernel(
    const float* __restrict__ img1, const float* __restrict__ img2,
    double* __restrict__ accum) {
  constexpr float GA[KS] = {
      0.00102838f, 0.00759884f, 0.03600087f, 0.10936069f, 0.21300553f,
      0.26601172f, 0.21300553f, 0.10936069f, 0.03600087f, 0.00759884f,
      0.00102838f};
  const float C1v = 1e-4f, C2v = 9e-4f;

  const int c  = threadIdx.x;          // column 0..511
  const int r0 = blockIdx.x * TH;      // first output row of strip
  const int b  = blockIdx.y;           // batch index

  const float* __restrict__ p1 = img1 + (size_t)b * (HH * WW);
  const float* __restrict__ p2 = img2 + (size_t)b * (HH * WW);

  // px x -> float2 slot x+6; float4 pair view: pair pi = slots 2pi,2pi+1.
  __shared__ __align__(16) float2 s2[2][4][NP2];
  __shared__ float wsum[8];

  // Zero horizontal pads of both buffers once (slots 0..5 and 518..523).
  if (c < 12) {
    const int idx = (c < 6) ? c : (512 + c);
#pragma unroll
    for (int bi = 0; bi < 2; ++bi)
#pragma unroll
      for (int r = 0; r < 4; ++r) s2[bi][r][idx] = make_float2(0.f, 0.f);
  }

  // Per-thread horizontal weights: reads deliver 12 px starting at
  // px c-6 (even c) or c-5 (odd c); tap j of the window is G[j].
  const bool oddc = (c & 1);
  const float w0  = oddc ? GA[0]  : 0.f;
  const float w1  = oddc ? GA[1]  : GA[0];
  const float w2  = oddc ? GA[2]  : GA[1];
  const float w3  = oddc ? GA[3]  : GA[2];
  const float w4  = oddc ? GA[4]  : GA[3];
  const float w5  = oddc ? GA[5]  : GA[4];
  const float w6  = oddc ? GA[6]  : GA[5];
  const float w7  = oddc ? GA[7]  : GA[6];
  const float w8  = oddc ? GA[8]  : GA[7];
  const float w9  = oddc ? GA[9]  : GA[8];
  const float w10 = oddc ? GA[10] : GA[9];
  const float w11 = oddc ? 0.f    : GA[10];

  const int pr0 = (c + 1) >> 1;        // first float4 pair of the window

  // Ring: 44 named scalars; slot s holds h-conv of input row rc, rc%11==s.
#define DECLR(s) float zA##s = 0.f, zB##s = 0.f, zQ##s = 0.f, zP##s = 0.f;
  DECLR(0) DECLR(1) DECLR(2) DECLR(3) DECLR(4) DECLR(5)
  DECLR(6) DECLR(7) DECLR(8) DECLR(9) DECLR(10)

  float pa0, pa1, pa2, pa3, pb0, pb1, pb2, pb3;   // prefetch regs
  float local = 0.f;

  // Load chunk k_ rows into named regs (rows >= NIN constexpr-cut; row
  // validity is block-uniform).
#define LD1(k_, j_)                                                     \
  {                                                                     \
    constexpr int rc_ = 4 * (k_) + (j_);                                \
    pa##j_ = 0.f; pb##j_ = 0.f;                                         \
    if constexpr (rc_ < NIN) {                                          \
      const int rr_ = r0 - PADK + rc_;                                  \
      if ((unsigned)rr_ < HH) {                                         \
        const int off_ = rr_ * WW + c;                                  \
        pa##j_ = p1[off_];                                              \
        pb##j_ = p2[off_];                                              \
      }                                                                 \
    }                                                                   \
  }
#define LOADC(k_) { LD1(k_, 0) LD1(k_, 1) LD1(k_, 2) LD1(k_, 3) }

  // Stage chunk k_ into buffer k_&1: float2{a,b}, one ds_write_b64/row.
#define WR1(k_, j_)                                                     \
  {                                                                     \
    constexpr int rc_ = 4 * (k_) + (j_);                                \
    if constexpr (rc_ < NIN)                                            \
      s2[(k_) & 1][j_][c + 6] = make_float2(pa##j_, pb##j_);            \
  }
#define WRITEC(k_) { WR1(k_, 0) WR1(k_, 1) WR1(k_, 2) WR1(k_, 3) }

  // One pixel {a,b} with weight w_: recompute q,p, 4 fma into accums.
#define HPX(aa_, bb2_, w_)                                              \
  {                                                                     \
    const float q_ = fmaf(aa_, aa_, bb2_ * bb2_);                       \
    const float p_ = aa_ * bb2_;                                        \
    h1 = fmaf(w_, aa_, h1); h2 = fmaf(w_, bb2_, h2);                    \
    hq = fmaf(w_, q_, hq);  hp = fmaf(w_, p_, hp);                      \
  }
#define HPAIR(kk_, wA_, wB_)                                            \
  {                                                                     \
    const float4 v = r4_[pr0 + kk_];                                    \
    HPX(v.x, v.y, wA_) HPX(v.z, v.w, wB_)                               \
  }

  // Horizontal 11-tap conv of LDS row j_ of buffer bb_: 6 b128 reads,
  // 12 px, result -> ring slot S (named).
#define HBODY(bb_, j_, S)                                               \
  {                                                                     \
    const float4* r4_ =                                                 \
        reinterpret_cast<const float4*>(&s2[bb_][j_][0]);               \
    float h1 = 0.f, h2 = 0.f, hq = 0.f, hp = 0.f;                       \
    HPAIR(0, w0, w1)  HPAIR(1, w2, w3)  HPAIR(2, w4, w5)                \
    HPAIR(3, w6, w7)  HPAIR(4, w8, w9)  HPAIR(5, w10, w11)              \
    zA##S = h1; zB##S = h2; zQ##S = hq; zP##S = hp;                     \
  }

  // Vertical conv: explicit rotation, slot names literal.
#define VC(P, s0,s1,s2v,s3,s4v,s5,s6v,s7,s8,s9,s10)                     \
  fmaf(GA[10], P##s10, fmaf(GA[9], P##s9, fmaf(GA[8], P##s8,            \
  fmaf(GA[7], P##s7, fmaf(GA[6], P##s6v, fmaf(GA[5], P##s5,             \
  fmaf(GA[4], P##s4v, fmaf(GA[3], P##s3, fmaf(GA[2], P##s2v,            \
  fmaf(GA[1], P##s1, GA[0] * P##s0))))))))))

#define VOUTBODY(s0,s1,s2v,s3,s4v,s5,s6v,s7,s8,s9,s10)                  \
  {                                                                     \
    const float m1 = VC(zA, s0,s1,s2v,s3,s4v,s5,s6v,s7,s8,s9,s10);      \
    const float m2 = VC(zB, s0,s1,s2v,s3,s4v,s5,s6v,s7,s8,s9,s10);      \
    const float mq = VC(zQ, s0,s1,s2v,s3,s4v,s5,s6v,s7,s8,s9,s10);      \
    const float mp = VC(zP, s0,s1,s2v,s3,s4v,s5,s6v,s7,s8,s9,s10);      \
    const float m1s = m1 * m1, m2s = m2 * m2, m12 = m1 * m2;            \
    const float s12 = mp - m12;                                         \
    const float sqq = mq - m1s - m2s;                                   \
    const float num = fmaf(2.f, m12, C1v) * fmaf(2.f, s12, C2v);        \
    const float den = (m1s + m2s + C1v) * (sqq + C2v);                  \
    local = fmaf(num, __builtin_amdgcn_rcpf(den), local);               \
  }

#define ROT0  0,1,2,3,4,5,6,7,8,9,10
#define ROT1  1,2,3,4,5,6,7,8,9,10,0
#define ROT2  2,3,4,5,6,7,8,9,10,0,1
#define ROT3  3,4,5,6,7,8,9,10,0,1,2
#define ROT4  4,5,6,7,8,9,10,0,1,2,3
#define ROT5  5,6,7,8,9,10,0,1,2,3,4
#define ROT6  6,7,8,9,10,0,1,2,3,4,5
#define ROT7  7,8,9,10,0,1,2,3,4,5,6
#define ROT8  8,9,10,0,1,2,3,4,5,6,7
#define ROT9  9,10,0,1,2,3,4,5,6,7,8
#define ROT10 10,0,1,2,3,4,5,6,7,8,9
#define VOUTE(...) VOUTBODY(__VA_ARGS__)

#define ROWH(bb_, j_, S)      { HBODY(bb_, j_, S) }
#define ROWO(bb_, j_, S, R_)  { HBODY(bb_, j_, S) VOUTE(R_) }

  // Prologue: prefetch chunk 0.
  LOADC(0)

  // Per chunk ii (buf = ii&1): write staged regs; ONE barrier; prefetch
  // chunk ii+1 (latency hides under this chunk's compute); compute the
  // 4 rows. rc = 4*ii+j; ring slot S = rc%11; output row rc-10 emitted
  // when rc >= 10 using rotation start (rc+1)%11.
  // ii=0: rc 0-3
  WRITEC(0) __syncthreads(); LOADC(1)
  ROWH(0,0,0) ROWH(0,1,1) ROWH(0,2,2) ROWH(0,3,3)
  // ii=1: rc 4-7
  WRITEC(1) __syncthreads(); LOADC(2)
  ROWH(1,0,4) ROWH(1,1,5) ROWH(1,2,6) ROWH(1,3,7)
  // ii=2: rc 8-11 (rc10,11 -> output rows 0,1)
  WRITEC(2) __syncthreads(); LOADC(3)
  ROWH(0,0,8) ROWH(0,1,9)
  ROWO(0,2,10, ROT0) ROWO(0,3,0, ROT1)
  // ii=3: rc 12-15
  WRITEC(3) __syncthreads(); LOADC(4)
  ROWO(1,0,1, ROT2) ROWO(1,1,2, ROT3) ROWO(1,2,3, ROT4) ROWO(1,3,4, ROT5)
  // ii=4: rc 16-19
  WRITEC(4) __syncthreads(); LOADC(5)
  ROWO(0,0,5, ROT6) ROWO(0,1,6, ROT7) ROWO(0,2,7, ROT8) ROWO(0,3,8, ROT9)
  // ii=5: rc 20-23
  WRITEC(5) __syncthreads(); LOADC(6)
  ROWO(1,0,9, ROT10) ROWO(1,1,10, ROT0) ROWO(1,2,0, ROT1) ROWO(1,3,1, ROT2)
  // ii=6: rc 24-27
  WRITEC(6) __syncthreads(); LOADC(7)
  ROWO(0,0,2, ROT3) ROWO(0,1,3, ROT4) ROWO(0,2,4, ROT5) ROWO(0,3,5, ROT6)
  // ii=7: rc 28-31
  WRITEC(7) __syncthreads(); LOADC(8)
  ROWO(1,0,6, ROT7) ROWO(1,1,7, ROT8) ROWO(1,2,8, ROT9) ROWO(1,3,9, ROT10)
  // ii=8: rc 32-35
  WRITEC(8) __syncthreads(); LOADC(9)
  ROWO(0,0,10, ROT0) ROWO(0,1,0, ROT1) ROWO(0,2,1, ROT2) ROWO(0,3,2, ROT3)
  // ii=9: rc 36-39
  WRITEC(9) __syncthreads(); LOADC(10)
  ROWO(1,0,3, ROT4) ROWO(1,1,4, ROT5) ROWO(1,2,5, ROT6) ROWO(1,3,6, ROT7)
  // ii=10: rc 40,41 (output rows 30,31; rc 42,43 constexpr-cut)
  WRITEC(10) __syncthreads();
  ROWO(0,0,7, ROT8) ROWO(0,1,8, ROT9)

  // Block reduction: wave64 shuffle -> LDS -> one double atomic per block.
#pragma unroll
  for (int off = 32; off > 0; off >>= 1) local += __shfl_down(local, off, 64);
  const int wave = threadIdx.x >> 6;
  const int lane = threadIdx.x & 63;
  if (lane == 0) wsum[wave] = local;
  __syncthreads();
  if (threadIdx.x == 0) {
    float s = 0.f;
#pragma unroll
    for (int w = 0; w < 8; ++w) s += wsum[w];
    atomicAdd(accum, (double)s);
  }
}

__global__ void ssim_final_kernel(const double* __restrict__ accum,
                                  float* __restrict__ out) {
  out[0] = 1.0f - (float)(accum[0] / NPIX);
}

extern "C" void kernel_launch(void* const* d_in, const int* in_sizes, int n_in,
                              void* d_out, int out_size, void* d_ws, size_t ws_size,
                              hipStream_t stream) {
  const float* img1 = (const float*)d_in[0];
  const float* img2 = (const float*)d_in[1];
  double* accum = (double*)d_ws;
  hipMemsetAsync(accum, 0, sizeof(double), stream);

  dim3 grid(HH / TH, BATCH);
  ssim_main_kernel<<<grid, 512, 0, stream>>>(img1, img2, accum);
  ssim_final_kernel<<<1, 1, 0, stream>>>(accum, (float*)d_out);
}